// Round 1
// baseline (1750.542 us; speedup 1.0000x reference)
//
#include <hip/hip_runtime.h>

// MinkowskiUnion: out[map_out[i]] += feat[map_in[i]] for two input tensors.
// C = 64 floats per row. 16 threads/row, float4 per thread.

#define ROW_C 64

__global__ void scatter_add_rows(const float* __restrict__ feat,
                                 const int* __restrict__ map_in,
                                 const int* __restrict__ map_out,
                                 float* __restrict__ out,
                                 int n_rows) {
    int gid = blockIdx.x * blockDim.x + threadIdx.x;
    int row = gid >> 4;            // 16 threads per row
    if (row >= n_rows) return;
    int sub = (gid & 15) << 2;     // element offset within row (float4 granularity)

    int in_r  = map_in[row];       // 16 lanes read same addr -> broadcast
    int out_r = map_out[row];

    const float4 v = *reinterpret_cast<const float4*>(feat + (size_t)in_r * ROW_C + sub);
    float* o = out + (size_t)out_r * ROW_C + sub;

    // Native global_atomic_add_f32 (no CAS loop) — fine on coarse-grained device mem.
    unsafeAtomicAdd(o + 0, v.x);
    unsafeAtomicAdd(o + 1, v.y);
    unsafeAtomicAdd(o + 2, v.z);
    unsafeAtomicAdd(o + 3, v.w);
}

extern "C" void kernel_launch(void* const* d_in, const int* in_sizes, int n_in,
                              void* d_out, int out_size, void* d_ws, size_t ws_size,
                              hipStream_t stream) {
    const float* feat1    = (const float*)d_in[0];
    const float* feat2    = (const float*)d_in[1];
    const int*   map1_in  = (const int*)d_in[2];
    const int*   map1_out = (const int*)d_in[3];
    const int*   map2_in  = (const int*)d_in[4];
    const int*   map2_out = (const int*)d_in[5];
    float* out = (float*)d_out;

    const int n1 = in_sizes[2];   // N1 rows
    const int n2 = in_sizes[4];   // N2 rows

    // Zero the output (harness poisons it; duplicates in map_out require accumulation).
    hipMemsetAsync(out, 0, (size_t)out_size * sizeof(float), stream);

    const int block = 256;
    {
        long long threads = (long long)n1 * 16;
        int grid = (int)((threads + block - 1) / block);
        scatter_add_rows<<<grid, block, 0, stream>>>(feat1, map1_in, map1_out, out, n1);
    }
    {
        long long threads = (long long)n2 * 16;
        int grid = (int)((threads + block - 1) / block);
        scatter_add_rows<<<grid, block, 0, stream>>>(feat2, map2_in, map2_out, out, n2);
    }
}

// Round 2
// 539.268 us; speedup vs baseline: 3.2461x; 3.2461x over previous
//
#include <hip/hip_runtime.h>

// MinkowskiUnion: out[map_out[i]] += feat[map_in[i]] for two input tensors.
// Strategy: invert the scatter into a gather via counting-sort CSR:
//   counts[r]  = #inputs landing on output row r        (int atomics, cheap)
//   cursor[r]  = exclusive-scan(counts)  -> after fill, cursor[r] = end offset
//   csr[]      = packed (tensor_bit<<30 | in_row) entries grouped by out row
//   gather-sum = each output row sums its sources, writes once. No f32 atomics.

#define ROW_C 64
#define SCAN_T 256
#define SCAN_PER 16
#define SCAN_CHUNK (SCAN_T * SCAN_PER)   // 4096 counts per block

// ---------- fallback path (atomic scatter) ----------
__global__ void scatter_add_rows(const float* __restrict__ feat,
                                 const int* __restrict__ map_in,
                                 const int* __restrict__ map_out,
                                 float* __restrict__ out,
                                 int n_rows) {
    int gid = blockIdx.x * blockDim.x + threadIdx.x;
    int row = gid >> 4;
    if (row >= n_rows) return;
    int sub = (gid & 15) << 2;
    int in_r  = map_in[row];
    int out_r = map_out[row];
    const float4 v = *reinterpret_cast<const float4*>(feat + (size_t)in_r * ROW_C + sub);
    float* o = out + (size_t)out_r * ROW_C + sub;
    unsafeAtomicAdd(o + 0, v.x);
    unsafeAtomicAdd(o + 1, v.y);
    unsafeAtomicAdd(o + 2, v.z);
    unsafeAtomicAdd(o + 3, v.w);
}

// ---------- CSR path ----------
__global__ void k_hist(const int* __restrict__ map_out, int n, int* __restrict__ counts) {
    int i = blockIdx.x * blockDim.x + threadIdx.x;
    if (i < n) atomicAdd(&counts[map_out[i]], 1);
}

__global__ void k_partial(const int* __restrict__ counts, int M, int* __restrict__ bsum) {
    __shared__ int lds[SCAN_T];
    int base = blockIdx.x * SCAN_CHUNK + threadIdx.x * SCAN_PER;
    int s = 0;
#pragma unroll
    for (int k = 0; k < SCAN_PER; k++) { int i = base + k; if (i < M) s += counts[i]; }
    lds[threadIdx.x] = s; __syncthreads();
    for (int off = SCAN_T / 2; off > 0; off >>= 1) {
        if (threadIdx.x < off) lds[threadIdx.x] += lds[threadIdx.x + off];
        __syncthreads();
    }
    if (threadIdx.x == 0) bsum[blockIdx.x] = lds[0];
}

// single block: exclusive scan of nblk (<=512) block sums in place
__global__ void k_scan_bsum(int* __restrict__ bsum, int nblk) {
    __shared__ int lds[512];
    int t = threadIdx.x;
    lds[t] = (t < nblk) ? bsum[t] : 0;
    __syncthreads();
    for (int off = 1; off < 512; off <<= 1) {
        int v = (t >= off) ? lds[t - off] : 0;
        __syncthreads();
        lds[t] += v;
        __syncthreads();
    }
    if (t < nblk) bsum[t] = (t == 0) ? 0 : lds[t - 1];
}

__global__ void k_offsets(const int* __restrict__ counts, int M,
                          const int* __restrict__ bsum, int* __restrict__ cursor) {
    __shared__ int lds[SCAN_T];
    int base = blockIdx.x * SCAN_CHUNK + threadIdx.x * SCAN_PER;
    int c[SCAN_PER]; int s = 0;
#pragma unroll
    for (int k = 0; k < SCAN_PER; k++) { int i = base + k; c[k] = (i < M) ? counts[i] : 0; s += c[k]; }
    lds[threadIdx.x] = s; __syncthreads();
    for (int off = 1; off < SCAN_T; off <<= 1) {
        int v = (threadIdx.x >= off) ? lds[threadIdx.x - off] : 0;
        __syncthreads();
        lds[threadIdx.x] += v;
        __syncthreads();
    }
    int prefix = bsum[blockIdx.x] + ((threadIdx.x == 0) ? 0 : lds[threadIdx.x - 1]);
#pragma unroll
    for (int k = 0; k < SCAN_PER; k++) { int i = base + k; if (i < M) cursor[i] = prefix; prefix += c[k]; }
}

__global__ void k_fill(const int* __restrict__ map_in, const int* __restrict__ map_out,
                       int n, int tbit, int* __restrict__ cursor, int* __restrict__ csr) {
    int i = blockIdx.x * blockDim.x + threadIdx.x;
    if (i >= n) return;
    int r = map_out[i];
    int pos = atomicAdd(&cursor[r], 1);
    csr[pos] = map_in[i] | tbit;
}

__global__ void k_gather(const float* __restrict__ feat1, const float* __restrict__ feat2,
                         const int* __restrict__ counts, const int* __restrict__ cursor,
                         const int* __restrict__ csr, float* __restrict__ out, int M) {
    int gid = blockIdx.x * blockDim.x + threadIdx.x;
    int row = gid >> 4;            // 16 threads per output row
    if (row >= M) return;
    int sub = (gid & 15) << 2;

    int cnt = counts[row];
    int end = cursor[row];         // after fill: start + cnt
    int start = end - cnt;

    float4 acc = {0.f, 0.f, 0.f, 0.f};
    for (int k = 0; k < cnt; k++) {
        int e = csr[start + k];    // broadcast across the 16 lanes
        const float* f = (e & (1 << 30)) ? feat2 : feat1;
        int in_r = e & 0x3FFFFFFF & ~(1 << 30);
        in_r = e & ((1 << 30) - 1);
        float4 v = *reinterpret_cast<const float4*>(f + (size_t)in_r * ROW_C + sub);
        acc.x += v.x; acc.y += v.y; acc.z += v.z; acc.w += v.w;
    }
    *reinterpret_cast<float4*>(out + (size_t)row * ROW_C + sub) = acc;
}

extern "C" void kernel_launch(void* const* d_in, const int* in_sizes, int n_in,
                              void* d_out, int out_size, void* d_ws, size_t ws_size,
                              hipStream_t stream) {
    const float* feat1    = (const float*)d_in[0];
    const float* feat2    = (const float*)d_in[1];
    const int*   map1_in  = (const int*)d_in[2];
    const int*   map1_out = (const int*)d_in[3];
    const int*   map2_in  = (const int*)d_in[4];
    const int*   map2_out = (const int*)d_in[5];
    float* out = (float*)d_out;

    const int n1 = in_sizes[2];
    const int n2 = in_sizes[4];
    const int M  = out_size / ROW_C;
    const int ntot = n1 + n2;
    const int nblk = (M + SCAN_CHUNK - 1) / SCAN_CHUNK;

    const size_t need = (size_t)(2 * (size_t)M + (size_t)ntot + (size_t)nblk) * sizeof(int);
    const int block = 256;

    if (ws_size < need || nblk > 512) {
        // fallback: atomic scatter
        hipMemsetAsync(out, 0, (size_t)out_size * sizeof(float), stream);
        int grid1 = (int)(((long long)n1 * 16 + block - 1) / block);
        int grid2 = (int)(((long long)n2 * 16 + block - 1) / block);
        scatter_add_rows<<<grid1, block, 0, stream>>>(feat1, map1_in, map1_out, out, n1);
        scatter_add_rows<<<grid2, block, 0, stream>>>(feat2, map2_in, map2_out, out, n2);
        return;
    }

    int* counts = (int*)d_ws;          // M
    int* cursor = counts + M;          // M
    int* csr    = cursor + M;          // n1+n2
    int* bsum   = csr + ntot;          // nblk

    hipMemsetAsync(counts, 0, (size_t)M * sizeof(int), stream);

    k_hist<<<(n1 + block - 1) / block, block, 0, stream>>>(map1_out, n1, counts);
    k_hist<<<(n2 + block - 1) / block, block, 0, stream>>>(map2_out, n2, counts);

    k_partial<<<nblk, SCAN_T, 0, stream>>>(counts, M, bsum);
    k_scan_bsum<<<1, 512, 0, stream>>>(bsum, nblk);
    k_offsets<<<nblk, SCAN_T, 0, stream>>>(counts, M, bsum, cursor);

    k_fill<<<(n1 + block - 1) / block, block, 0, stream>>>(map1_in, map1_out, n1, 0, cursor, csr);
    k_fill<<<(n2 + block - 1) / block, block, 0, stream>>>(map2_in, map2_out, n2, 1 << 30, cursor, csr);

    int gridg = (int)(((long long)M * 16 + block - 1) / block);
    k_gather<<<gridg, block, 0, stream>>>(feat1, feat2, counts, cursor, csr, out, M);
}

// Round 3
// 484.534 us; speedup vs baseline: 3.6128x; 1.1130x over previous
//
#include <hip/hip_runtime.h>

// MinkowskiUnion: out[map_out[i]] += feat[map_in[i]] for two input tensors.
// Preferred path: K=4 direct slot table + overflow list (no histogram/scan):
//   cnt[r]      = atomic counter per output row
//   slots[4r+p] = packed (tensor_bit<<30 | in_row) for p<4
//   ovf list    = rare entries with p>=4, applied via f32 atomics after gather
//   gather      = each out row sums <=4 slot rows, writes once (no f32 atomics)
// Fallbacks: CSR counting-sort (round-2 path), then plain atomic scatter.

#define ROW_C 64
#define TBIT (1 << 30)
#define OVF_CAP (1 << 20)
#define SCAN_T 256
#define SCAN_PER 16
#define SCAN_CHUNK (SCAN_T * SCAN_PER)

// ---------- slot path ----------
__global__ void k_fill_slots(const int* __restrict__ m1i, const int* __restrict__ m1o,
                             const int* __restrict__ m2i, const int* __restrict__ m2o,
                             int n1, int n2,
                             int* __restrict__ cnt, int* __restrict__ slots,
                             int* __restrict__ ovf, int* __restrict__ ovf_n) {
    int i = blockIdx.x * blockDim.x + threadIdx.x;
    int r, v;
    if (i < n1) { r = m1o[i]; v = m1i[i]; }
    else {
        int j = i - n1;
        if (j >= n2) return;
        r = m2o[j]; v = m2i[j] | TBIT;
    }
    int pos = atomicAdd(&cnt[r], 1);
    if (pos < 4) {
        slots[(r << 2) + pos] = v;
    } else {
        int p = atomicAdd(ovf_n, 1);
        if (p < OVF_CAP) { ovf[2 * p] = r; ovf[2 * p + 1] = v; }
    }
}

__global__ void k_gather_slots(const float* __restrict__ feat1, const float* __restrict__ feat2,
                               const int* __restrict__ cnt, const int* __restrict__ slots,
                               float* __restrict__ out, int M) {
    int gid = blockIdx.x * blockDim.x + threadIdx.x;
    int row = gid >> 4;                 // 16 threads per output row
    if (row >= M) return;
    int sub = (gid & 15) << 2;

    int c = cnt[row];
    if (c > 4) c = 4;
    const int4 s = *reinterpret_cast<const int4*>(slots + (row << 2));  // broadcast
    int e[4] = { s.x, s.y, s.z, s.w };

    float4 acc = {0.f, 0.f, 0.f, 0.f};
#pragma unroll
    for (int k = 0; k < 4; k++) {
        if (k < c) {
            int v = e[k];
            const float* f = (v & TBIT) ? feat2 : feat1;
            int in_r = v & (TBIT - 1);
            float4 x = *reinterpret_cast<const float4*>(f + (size_t)in_r * ROW_C + sub);
            acc.x += x.x; acc.y += x.y; acc.z += x.z; acc.w += x.w;
        }
    }
    *reinterpret_cast<float4*>(out + (size_t)row * ROW_C + sub) = acc;
}

__global__ void k_overflow(const int* __restrict__ ovf_n, const int* __restrict__ ovf,
                           const float* __restrict__ feat1, const float* __restrict__ feat2,
                           float* __restrict__ out) {
    int total = *ovf_n;
    if (total > OVF_CAP) total = OVF_CAP;
    int stride = gridDim.x * blockDim.x;
    for (int idx = blockIdx.x * blockDim.x + threadIdx.x; idx < total * 16; idx += stride) {
        int e = idx >> 4;
        int sub = (idx & 15) << 2;
        int r = ovf[2 * e];
        int v = ovf[2 * e + 1];
        const float* f = (v & TBIT) ? feat2 : feat1;
        int in_r = v & (TBIT - 1);
        float4 x = *reinterpret_cast<const float4*>(f + (size_t)in_r * ROW_C + sub);
        float* o = out + (size_t)r * ROW_C + sub;
        unsafeAtomicAdd(o + 0, x.x);
        unsafeAtomicAdd(o + 1, x.y);
        unsafeAtomicAdd(o + 2, x.z);
        unsafeAtomicAdd(o + 3, x.w);
    }
}

// ---------- CSR fallback ----------
__global__ void k_hist(const int* __restrict__ map_out, int n, int* __restrict__ counts) {
    int i = blockIdx.x * blockDim.x + threadIdx.x;
    if (i < n) atomicAdd(&counts[map_out[i]], 1);
}

__global__ void k_partial(const int* __restrict__ counts, int M, int* __restrict__ bsum) {
    __shared__ int lds[SCAN_T];
    int base = blockIdx.x * SCAN_CHUNK + threadIdx.x * SCAN_PER;
    int s = 0;
#pragma unroll
    for (int k = 0; k < SCAN_PER; k++) { int i = base + k; if (i < M) s += counts[i]; }
    lds[threadIdx.x] = s; __syncthreads();
    for (int off = SCAN_T / 2; off > 0; off >>= 1) {
        if (threadIdx.x < off) lds[threadIdx.x] += lds[threadIdx.x + off];
        __syncthreads();
    }
    if (threadIdx.x == 0) bsum[blockIdx.x] = lds[0];
}

__global__ void k_scan_bsum(int* __restrict__ bsum, int nblk) {
    __shared__ int lds[512];
    int t = threadIdx.x;
    lds[t] = (t < nblk) ? bsum[t] : 0;
    __syncthreads();
    for (int off = 1; off < 512; off <<= 1) {
        int v = (t >= off) ? lds[t - off] : 0;
        __syncthreads();
        lds[t] += v;
        __syncthreads();
    }
    if (t < nblk) bsum[t] = (t == 0) ? 0 : lds[t - 1];
}

__global__ void k_offsets(const int* __restrict__ counts, int M,
                          const int* __restrict__ bsum, int* __restrict__ cursor) {
    __shared__ int lds[SCAN_T];
    int base = blockIdx.x * SCAN_CHUNK + threadIdx.x * SCAN_PER;
    int c[SCAN_PER]; int s = 0;
#pragma unroll
    for (int k = 0; k < SCAN_PER; k++) { int i = base + k; c[k] = (i < M) ? counts[i] : 0; s += c[k]; }
    lds[threadIdx.x] = s; __syncthreads();
    for (int off = 1; off < SCAN_T; off <<= 1) {
        int v = (threadIdx.x >= off) ? lds[threadIdx.x - off] : 0;
        __syncthreads();
        lds[threadIdx.x] += v;
        __syncthreads();
    }
    int prefix = bsum[blockIdx.x] + ((threadIdx.x == 0) ? 0 : lds[threadIdx.x - 1]);
#pragma unroll
    for (int k = 0; k < SCAN_PER; k++) { int i = base + k; if (i < M) cursor[i] = prefix; prefix += c[k]; }
}

__global__ void k_fill(const int* __restrict__ map_in, const int* __restrict__ map_out,
                       int n, int tbit, int* __restrict__ cursor, int* __restrict__ csr) {
    int i = blockIdx.x * blockDim.x + threadIdx.x;
    if (i >= n) return;
    int r = map_out[i];
    int pos = atomicAdd(&cursor[r], 1);
    csr[pos] = map_in[i] | tbit;
}

__global__ void k_gather(const float* __restrict__ feat1, const float* __restrict__ feat2,
                         const int* __restrict__ counts, const int* __restrict__ cursor,
                         const int* __restrict__ csr, float* __restrict__ out, int M) {
    int gid = blockIdx.x * blockDim.x + threadIdx.x;
    int row = gid >> 4;
    if (row >= M) return;
    int sub = (gid & 15) << 2;

    int cnt = counts[row];
    int end = cursor[row];
    int start = end - cnt;

    float4 acc = {0.f, 0.f, 0.f, 0.f};
    for (int k = 0; k < cnt; k++) {
        int e = csr[start + k];
        const float* f = (e & TBIT) ? feat2 : feat1;
        int in_r = e & (TBIT - 1);
        float4 v = *reinterpret_cast<const float4*>(f + (size_t)in_r * ROW_C + sub);
        acc.x += v.x; acc.y += v.y; acc.z += v.z; acc.w += v.w;
    }
    *reinterpret_cast<float4*>(out + (size_t)row * ROW_C + sub) = acc;
}

// ---------- last-resort atomic scatter ----------
__global__ void scatter_add_rows(const float* __restrict__ feat,
                                 const int* __restrict__ map_in,
                                 const int* __restrict__ map_out,
                                 float* __restrict__ out,
                                 int n_rows) {
    int gid = blockIdx.x * blockDim.x + threadIdx.x;
    int row = gid >> 4;
    if (row >= n_rows) return;
    int sub = (gid & 15) << 2;
    int in_r  = map_in[row];
    int out_r = map_out[row];
    const float4 v = *reinterpret_cast<const float4*>(feat + (size_t)in_r * ROW_C + sub);
    float* o = out + (size_t)out_r * ROW_C + sub;
    unsafeAtomicAdd(o + 0, v.x);
    unsafeAtomicAdd(o + 1, v.y);
    unsafeAtomicAdd(o + 2, v.z);
    unsafeAtomicAdd(o + 3, v.w);
}

extern "C" void kernel_launch(void* const* d_in, const int* in_sizes, int n_in,
                              void* d_out, int out_size, void* d_ws, size_t ws_size,
                              hipStream_t stream) {
    const float* feat1    = (const float*)d_in[0];
    const float* feat2    = (const float*)d_in[1];
    const int*   map1_in  = (const int*)d_in[2];
    const int*   map1_out = (const int*)d_in[3];
    const int*   map2_in  = (const int*)d_in[4];
    const int*   map2_out = (const int*)d_in[5];
    float* out = (float*)d_out;

    const int n1 = in_sizes[2];
    const int n2 = in_sizes[4];
    const int M  = out_size / ROW_C;
    const int ntot = n1 + n2;
    const int block = 256;

    // ---- slot path ----
    // layout: cnt[M] | ovf_n[1] | pad[3] | slots[4M] | ovf[2*OVF_CAP]
    const size_t need_slots = ((size_t)M + 4 + 4 * (size_t)M + 2 * (size_t)OVF_CAP) * sizeof(int);
    if (ws_size >= need_slots && (M & 3) == 0) {
        int* cnt   = (int*)d_ws;
        int* ovf_n = cnt + M;
        int* slots = cnt + M + 4;
        int* ovf   = slots + 4 * (size_t)M;

        hipMemsetAsync(cnt, 0, (size_t)(M + 4) * sizeof(int), stream);

        int gridf = (ntot + block - 1) / block;
        k_fill_slots<<<gridf, block, 0, stream>>>(map1_in, map1_out, map2_in, map2_out,
                                                  n1, n2, cnt, slots, ovf, ovf_n);

        int gridg = (int)(((long long)M * 16 + block - 1) / block);
        k_gather_slots<<<gridg, block, 0, stream>>>(feat1, feat2, cnt, slots, out, M);

        k_overflow<<<1024, block, 0, stream>>>(ovf_n, ovf, feat1, feat2, out);
        return;
    }

    // ---- CSR fallback ----
    const int nblk = (M + SCAN_CHUNK - 1) / SCAN_CHUNK;
    const size_t need_csr = (size_t)(2 * (size_t)M + (size_t)ntot + (size_t)nblk) * sizeof(int);
    if (ws_size >= need_csr && nblk <= 512) {
        int* counts = (int*)d_ws;
        int* cursor = counts + M;
        int* csr    = cursor + M;
        int* bsum   = csr + ntot;

        hipMemsetAsync(counts, 0, (size_t)M * sizeof(int), stream);
        k_hist<<<(n1 + block - 1) / block, block, 0, stream>>>(map1_out, n1, counts);
        k_hist<<<(n2 + block - 1) / block, block, 0, stream>>>(map2_out, n2, counts);
        k_partial<<<nblk, SCAN_T, 0, stream>>>(counts, M, bsum);
        k_scan_bsum<<<1, 512, 0, stream>>>(bsum, nblk);
        k_offsets<<<nblk, SCAN_T, 0, stream>>>(counts, M, bsum, cursor);
        k_fill<<<(n1 + block - 1) / block, block, 0, stream>>>(map1_in, map1_out, n1, 0, cursor, csr);
        k_fill<<<(n2 + block - 1) / block, block, 0, stream>>>(map2_in, map2_out, n2, TBIT, cursor, csr);
        int gridg = (int)(((long long)M * 16 + block - 1) / block);
        k_gather<<<gridg, block, 0, stream>>>(feat1, feat2, counts, cursor, csr, out, M);
        return;
    }

    // ---- atomic scatter ----
    hipMemsetAsync(out, 0, (size_t)out_size * sizeof(float), stream);
    int grid1 = (int)(((long long)n1 * 16 + block - 1) / block);
    int grid2 = (int)(((long long)n2 * 16 + block - 1) / block);
    scatter_add_rows<<<grid1, block, 0, stream>>>(feat1, map1_in, map1_out, out, n1);
    scatter_add_rows<<<grid2, block, 0, stream>>>(feat2, map2_in, map2_out, out, n2);
}